// Round 14
// baseline (852.847 us; speedup 1.0000x reference)
//
#include <hip/hip_runtime.h>
#include <hip/hip_bf16.h>

// Problem constants (setup_inputs: B=8,S=2048,H=1024,A=512,N=10, t=5, s=400)
static constexpr int B_ = 8, S_ = 2048, H_ = 1024, A_ = 512;
static constexpr int M_ = B_ * S_;          // 16384 rows (b,s)
static constexpr int T_ = 6;                // t+1
static constexpr long HID_STRIDE = (long)M_ * H_;   // 16777216 elems
static constexpr long SC_STRIDE  = (long)M_ * 64;   // 1048576 elems

typedef __attribute__((ext_vector_type(4))) float f32x4;
typedef __attribute__((ext_vector_type(8))) short bf16x8;

__device__ __forceinline__ float bf2f(ushort u){ return __uint_as_float(((unsigned)u) << 16); }
__device__ __forceinline__ ushort f2bf(float f){
  __hip_bfloat16 h = __float2bfloat16(f);
  return __builtin_bit_cast(unsigned short, h);
}
__device__ __forceinline__ float geluf(float x){
  return 0.5f * x * (1.0f + erff(x * 0.70710678118654752440f));
}
__device__ __forceinline__ float sigm(float x){ return 1.0f / (1.0f + __expf(-x)); }

__device__ __forceinline__ void gload_lds16(const void* g, void* l){
  __builtin_amdgcn_global_load_lds((const __attribute__((address_space(1))) void*)g,
                                   (__attribute__((address_space(3))) void*)l, 16, 0, 0);
}

// ---------------- prep kernels ----------------

__global__ void gates_kernel(const float* __restrict__ efc1, const float* __restrict__ efc2,
                             const int* __restrict__ tptr, const int* __restrict__ sptr,
                             float* __restrict__ g1, float* __restrict__ g2)
{
  const int h = threadIdx.x;          // 0..1023
  const int t = *tptr;
  const float s = (float)(*sptr);
  #pragma unroll
  for (int ti = 0; ti < T_; ++ti) {
    const int task = (ti == 0) ? t : (ti - 1);
    const float scl = (ti == 0) ? s : 400.0f;
    g2[ti * H_ + h] = sigm(scl * efc2[task * H_ + h]);
    if (h < A_) g1[ti * A_ + h] = sigm(scl * efc1[task * A_ + h]);
  }
}

__global__ void kq_kernel(const float* __restrict__ etask, const float* __restrict__ q_w,
                          const float* __restrict__ q_b, const float* __restrict__ equery,
                          const float* __restrict__ ekey, const float* __restrict__ k_w,
                          const float* __restrict__ k_b,
                          const int* __restrict__ tptr, const int* __restrict__ sptr,
                          ushort* __restrict__ kqw, float* __restrict__ kqb)
{
  __shared__ float qg[16];
  const int d = blockIdx.x;           // 0..63
  const int tid = threadIdx.x;        // 256 threads
  const int t = *tptr;
  const float s = (float)(*sptr);
  if (tid < 16) {
    const int hp = tid * 64 + d;
    const float* et = etask + (long)t * H_;
    const float* qw = q_w + (long)hp * H_;
    float acc = 0.f;
    for (int i = 0; i < H_; ++i) acc += et[i] * qw[i];
    float qv = (acc + q_b[hp]) * sigm(s * equery[t * H_ + hp]);
    qg[tid] = qv * sigm(s * ekey[t * H_ + hp]);
  }
  __syncthreads();
  for (int hh = tid; hh < H_; hh += 256) {
    float acc = 0.f;
    #pragma unroll
    for (int n = 0; n < 16; ++n) acc += qg[n] * k_w[(long)(n * 64 + d) * H_ + hh];
    kqw[d * H_ + hh] = f2bf(acc);
  }
  if (tid == 0) {
    float acc = 0.f;
    #pragma unroll
    for (int n = 0; n < 16; ++n) acc += qg[n] * k_b[n * 64 + d];
    kqb[d] = acc;
  }
}

__global__ void conv_bf16(const float* __restrict__ in, ushort* __restrict__ outp, long n)
{
  long i = ((long)blockIdx.x * blockDim.x + threadIdx.x) * 4;
  const long stride = (long)gridDim.x * blockDim.x * 4;
  for (; i < n; i += stride) {
    float4 v = *(const float4*)(in + i);
    ushort4 o;
    o.x = f2bf(v.x); o.y = f2bf(v.y); o.z = f2bf(v.z); o.w = f2bf(v.w);
    *(ushort4*)(outp + i) = o;
  }
}

__global__ void conv_w2g(const float* __restrict__ fc2w, const float* __restrict__ g1,
                         ushort* __restrict__ W2g)
{
  const long total = (long)T_ * H_ * A_;
  long i = ((long)blockIdx.x * blockDim.x + threadIdx.x) * 4;
  if (i >= total) return;
  const int ti = (int)(i / ((long)H_ * A_));
  const long r = i - (long)ti * H_ * A_;
  const int a = (int)(r & (A_ - 1));
  float4 wv = *(const float4*)(fc2w + r);
  const float* g = g1 + ti * A_ + a;
  ushort4 o;
  o.x = f2bf(wv.x * g[0]); o.y = f2bf(wv.y * g[1]);
  o.z = f2bf(wv.z * g[2]); o.w = f2bf(wv.w * g[3]);
  *(ushort4*)(W2g + i) = o;
}

// Permuted gated V weight: row f (output feature) <- v_w[hp]*gv[hp], hp=(f&15)*64+(f>>4)
__global__ void conv_vw(const float* __restrict__ v_w, const float* __restrict__ v_b,
                        const float* __restrict__ evalue,
                        const int* __restrict__ tptr, const int* __restrict__ sptr,
                        ushort* __restrict__ vwb, float* __restrict__ vbg)
{
  const int t = *tptr;
  const float s = (float)(*sptr);
  long i = ((long)blockIdx.x * blockDim.x + threadIdx.x) * 4;
  if (i < (long)H_ * H_) {
    const int f = (int)(i >> 10);
    const int hp = ((f & 15) << 6) + (f >> 4);
    const float g = sigm(s * evalue[t * H_ + hp]);
    float4 wv = *(const float4*)(v_w + ((long)hp << 10) + (i & 1023));
    ushort4 o;
    o.x = f2bf(wv.x * g); o.y = f2bf(wv.y * g);
    o.z = f2bf(wv.z * g); o.w = f2bf(wv.w * g);
    *(ushort4*)(vwb + i) = o;
  }
  const long j = (long)blockIdx.x * blockDim.x + threadIdx.x;
  if (j < H_) {
    const int hp = (((int)j & 15) << 6) + ((int)j >> 4);
    vbg[j] = v_b[hp] * sigm(s * evalue[t * H_ + hp]);
  }
}

// ---------------- GEMM: C = epi(A @ B^T + bias) ----------------
// Best measured (round 8): 3-buffer single-barrier depth-2 pipeline; per step:
// vmcnt(N) -> barrier -> ds_read issue -> stage(t+2) -> lgkmcnt(0) -> MFMA.
// T2 XOR-swizzle (conflicts=0), T4 counted vmcnt, T5 setprio.
// EPI: 0 = gelu->bf16, 1 = gelu*scale[col]->bf16, 2 = (acc+bias)*postmul->f32
template<int BM, int BN, int EPI>
__global__ __launch_bounds__(256)
void gemm_bt(const ushort* __restrict__ A, const ushort* __restrict__ Bm,
             void* __restrict__ C, const float* __restrict__ bias,
             const float* __restrict__ scale,
             int M, int N, int K,
             long strideAz, long strideBz, long strideCz, int strideSz,
             float postmul)
{
  constexpr int BK = 32;
  constexpr int WM = BM / 2, WN = BN / 2;
  constexpr int MI = WM / 16, NI = WN / 16;
  constexpr int L = BM / 64 + BN / 64;     // loads per thread per stage
  __shared__ alignas(16) ushort As[3][BM * BK];
  __shared__ alignas(16) ushort Bs[3][BN * BK];

  const int z = blockIdx.z;
  A  += (long)z * strideAz;
  Bm += (long)z * strideBz;

  const int gx = gridDim.x, gy = gridDim.y;
  int flat = blockIdx.y * gx + blockIdx.x;
  const int nwg = gx * gy;
  if ((nwg & 7) == 0) flat = (flat & 7) * (nwg >> 3) + (flat >> 3);
  const int m0 = (flat / gy) * BM, n0 = (flat % gy) * BN;

  const int tid = threadIdx.x, lane = tid & 63, wid = tid >> 6;
  const int wr = wid >> 1, wc = wid & 1;
  const int srow = tid >> 2;
  const int scol = (tid & 3) * 8;
  const int scol_src = (((tid & 3) ^ ((tid >> 3) & 3))) * 8;

  auto stage = [&](int buf, int kk) {
    #pragma unroll
    for (int i = 0; i < BM / 64; ++i)
      gload_lds16(A + (long)(m0 + i * 64 + srow) * K + kk + scol_src,
                  &As[buf][(i * 64 + srow) * BK + scol]);
    #pragma unroll
    for (int i = 0; i < BN / 64; ++i)
      gload_lds16(Bm + (long)(n0 + i * 64 + srow) * K + kk + scol_src,
                  &Bs[buf][(i * 64 + srow) * BK + scol]);
  };

  f32x4 acc[MI][NI] = {};
  const int NT = K / BK;
  const int ks = (((lane >> 4) ^ ((lane >> 1) & 3))) * 8;

  stage(0, 0);
  stage(1, BK);

  int cur = 0;
  for (int t = 0; t < NT; ++t) {
    if (t + 1 < NT) {
      if constexpr (L == 4) asm volatile("s_waitcnt vmcnt(4)" ::: "memory");
      else                  asm volatile("s_waitcnt vmcnt(3)" ::: "memory");
    } else {
      asm volatile("s_waitcnt vmcnt(0)" ::: "memory");
    }
    __builtin_amdgcn_s_barrier();            // tile t staged; buf (cur-1) fully read
    __builtin_amdgcn_sched_barrier(0);

    bf16x8 af[MI], bfr[NI];
    #pragma unroll
    for (int m = 0; m < MI; ++m)
      af[m] = *(const bf16x8*)&As[cur][(wr * WM + m * 16 + (lane & 15)) * BK + ks];
    #pragma unroll
    for (int n = 0; n < NI; ++n)
      bfr[n] = *(const bf16x8*)&Bs[cur][(wc * WN + n * 16 + (lane & 15)) * BK + ks];
    __builtin_amdgcn_sched_barrier(0);       // pin: ds_reads issue before stage

    if (t + 2 < NT) {
      int nb = cur + 2; if (nb >= 3) nb -= 3;
      stage(nb, (t + 2) * BK);               // overlaps ds_read latency
    }

    asm volatile("s_waitcnt lgkmcnt(0)" ::: "memory");
    __builtin_amdgcn_sched_barrier(0);

    __builtin_amdgcn_s_setprio(1);
    #pragma unroll
    for (int m = 0; m < MI; ++m)
      #pragma unroll
      for (int n = 0; n < NI; ++n)
        acc[m][n] = __builtin_amdgcn_mfma_f32_16x16x32_bf16(af[m], bfr[n], acc[m][n], 0, 0, 0);
    __builtin_amdgcn_s_setprio(0);
    ++cur; if (cur >= 3) cur = 0;
  }

  const float* sc = (EPI == 1) ? (scale + (long)z * strideSz) : nullptr;
  #pragma unroll
  for (int m = 0; m < MI; ++m) {
    #pragma unroll
    for (int n = 0; n < NI; ++n) {
      const int col = n0 + wc * WN + n * 16 + (lane & 15);
      const float bv = bias[col];
      #pragma unroll
      for (int r = 0; r < 4; ++r) {
        const int row = m0 + wr * WM + m * 16 + (lane >> 4) * 4 + r;
        const float v = acc[m][n][r] + bv;
        const long ci = (long)z * strideCz + (long)row * N + col;
        if constexpr (EPI == 0) {
          ((ushort*)C)[ci] = f2bf(geluf(v));
        } else if constexpr (EPI == 1) {
          ((ushort*)C)[ci] = f2bf(geluf(v) * sc[col]);
        } else {
          ((float*)C)[ci] = v * postmul;
        }
      }
    }
  }
}

// ---------------- fused softmax + V-GEMM + context + residual ----------------
// LDS-BW fix: B (vwb, 2 MiB, L2-resident) fragments are loaded DIRECTLY from
// global into registers (double-buffered one step ahead) -- halves LDS traffic
// (which was ~92% of the measured 85 B/cyc ds_read_b128 ceiling). LDS holds
// only A (3-buffer, 24 KB) + p (24 KB) = 48 KB -> up to 3 blocks/CU.
// Steady-state vmcnt(6): newer-than-stageA(t) = loadB(t):4 + stageA(t+1):2.
__global__ __launch_bounds__(256)
void fusedv_kernel(const ushort* __restrict__ hidb, const ushort* __restrict__ vwb,
                   const float* __restrict__ scB, const float* __restrict__ vbg,
                   const float* __restrict__ x, float* __restrict__ out)
{
  constexpr int BM = 128, BN = 128, BK = 32;
  constexpr int WM = 64, WN = 64, MI = 4, NI = 4;
  constexpr int NT = T_ * 32;
  __shared__ alignas(16) ushort As[3][BM * BK];      // 24 KB
  __shared__ alignas(16) float p_lds[T_ * BM * 8];   // 24 KB

  const int gx = gridDim.x, gy = gridDim.y;   // (128, 8)
  int flat = blockIdx.y * gx + blockIdx.x;
  const int nwg = gx * gy;
  flat = (flat & 7) * (nwg >> 3) + (flat >> 3);
  const int m0 = (flat / gy) * BM, n0 = (flat % gy) * BN;
  const int d0 = n0 >> 4;

  const int tid = threadIdx.x, lane = tid & 63, wid = tid >> 6;
  const int wr = wid >> 1, wc = wid & 1;
  const int srow = tid >> 2;
  const int scol = (tid & 3) * 8;
  const int scol_src = (((tid & 3) ^ ((tid >> 3) & 3))) * 8;
  const int ks = (((lane >> 4) ^ ((lane >> 1) & 3))) * 8;

  auto stageA = [&](int buf, int kt) {
    const int ti = kt >> 5;
    const int kk = (kt & 31) << 5;
    const ushort* Ap = hidb + (long)ti * HID_STRIDE;
    #pragma unroll
    for (int i = 0; i < 2; ++i)
      gload_lds16(Ap + (long)(m0 + i * 64 + srow) * H_ + kk + scol_src,
                  &As[buf][(i * 64 + srow) * BK + scol]);
  };

  // B direct-from-global: lane reads 16B of row (n0+wc*64+n*16+(lane&15)),
  // k-chunk (lane>>4)*8. Natural layout (no swizzle needed; registers).
  const ushort* Bbase = vwb + (long)(n0 + wc * WN + (lane & 15)) * H_ + (lane >> 4) * 8;
  auto loadB = [&](int kt, bf16x8* dst) {
    const int kk = (kt & 31) << 5;
    #pragma unroll
    for (int n = 0; n < NI; ++n)
      dst[n] = *(const bf16x8*)(Bbase + (long)n * 16 * H_ + kk);
  };
  auto readA = [&](int buf, bf16x8* af) {
    #pragma unroll
    for (int m = 0; m < MI; ++m)
      af[m] = *(const bf16x8*)&As[buf][(wr * WM + m * 16 + (lane & 15)) * BK + ks];
  };

  // prologue: stage A-tile 0, softmax into p_lds, B(0) into regs, stage A-tile 1
  stageA(0, 0);
  #pragma unroll
  for (int c = 0; c < 4; ++c) {
    const int cell = tid + c * 256;          // 0..1023 = 128 rows x 8 d
    const int row = cell >> 3, dl = cell & 7;
    const long base = (long)(m0 + row) * 64 + d0 + dl;
    float v[T_]; float mx = -1e30f;
    #pragma unroll
    for (int ti = 0; ti < T_; ++ti) {
      v[ti] = scB[(long)ti * SC_STRIDE + base];
      mx = fmaxf(mx, v[ti]);
    }
    float sum = 0.f;
    #pragma unroll
    for (int ti = 0; ti < T_; ++ti) { v[ti] = __expf(v[ti] - mx); sum += v[ti]; }
    const float inv = 1.0f / sum;
    #pragma unroll
    for (int ti = 0; ti < T_; ++ti) p_lds[(ti * BM + row) * 8 + dl] = v[ti] * inv;
  }
  asm volatile("s_waitcnt lgkmcnt(0)" ::: "memory");  // p_lds writes retired
  bf16x8 bEven[NI], bOdd[NI];
  loadB(0, bEven);
  stageA(1, 1);

  const f32x4 zero = {};
  f32x4 ctx[MI][NI] = {};
  f32x4 acc[MI][NI] = {};

  int cur = 0;                               // buffer of even-step tile
  for (int t = 0; t < NT; t += 2) {
    // ---- even step kt=t: A from As[cur], B = bEven ----
    asm volatile("s_waitcnt vmcnt(6)" ::: "memory");   // stageA(t) done
    __builtin_amdgcn_s_barrier();            // tile t in LDS (and p_lds on t==0)
    __builtin_amdgcn_sched_barrier(0);

    bf16x8 afA[MI];
    readA(cur, afA);
    __builtin_amdgcn_sched_barrier(0);       // ds_reads issue first
    loadB(t + 1, bOdd);                      // t+1 < NT always (NT even)
    {
      int nb = cur + 2; if (nb >= 3) nb -= 3;
      if (t + 2 < NT) stageA(nb, t + 2);
    }
    asm volatile("s_waitcnt lgkmcnt(0)" ::: "memory");
    __builtin_amdgcn_sched_barrier(0);
    __builtin_amdgcn_s_setprio(1);
    #pragma unroll
    for (int m = 0; m < MI; ++m)
      #pragma unroll
      for (int n = 0; n < NI; ++n)
        acc[m][n] = __builtin_amdgcn_mfma_f32_16x16x32_bf16(afA[m], bEven[n], acc[m][n], 0, 0, 0);
    __builtin_amdgcn_s_setprio(0);

    // ---- odd step kt=t+1: A from As[cur+1], B = bOdd ----
    {
      int curO = cur + 1; if (curO >= 3) curO -= 3;
      if (t + 2 < NT) asm volatile("s_waitcnt vmcnt(6)" ::: "memory");
      else            asm volatile("s_waitcnt vmcnt(4)" ::: "memory");
      __builtin_amdgcn_s_barrier();          // tile t+1 in LDS; As[cur] free
      __builtin_amdgcn_sched_barrier(0);

      bf16x8 afB[MI];
      readA(curO, afB);
      __builtin_amdgcn_sched_barrier(0);
      if (t + 2 < NT) loadB(t + 2, bEven);
      if (t + 3 < NT) stageA(cur, t + 3);    // (t+3)%3 == t%3 == cur, now free
      asm volatile("s_waitcnt lgkmcnt(0)" ::: "memory");
      __builtin_amdgcn_sched_barrier(0);
      __builtin_amdgcn_s_setprio(1);
      #pragma unroll
      for (int m = 0; m < MI; ++m)
        #pragma unroll
        for (int n = 0; n < NI; ++n)
          acc[m][n] = __builtin_amdgcn_mfma_f32_16x16x32_bf16(afB[m], bOdd[n], acc[m][n], 0, 0, 0);
      __builtin_amdgcn_s_setprio(0);
    }

    if (((t + 1) & 31) == 31) {              // task boundary (odd step)
      const int ti = (t + 1) >> 5;
      #pragma unroll
      for (int m = 0; m < MI; ++m) {
        #pragma unroll
        for (int r = 0; r < 4; ++r) {
          const int rowl = wr * WM + m * 16 + (lane >> 4) * 4 + r;
          const f32x4 pv = *(const f32x4*)&p_lds[(ti * BM + rowl) * 8 + wc * 4];
          #pragma unroll
          for (int n = 0; n < NI; ++n)
            ctx[m][n][r] += pv[n] * acc[m][n][r];
        }
        #pragma unroll
        for (int n = 0; n < NI; ++n) acc[m][n] = zero;
      }
    }
    cur += 2; if (cur >= 3) cur -= 3;
  }

  #pragma unroll
  for (int m = 0; m < MI; ++m) {
    #pragma unroll
    for (int n = 0; n < NI; ++n) {
      const int col = n0 + wc * WN + n * 16 + (lane & 15);
      const float bv = vbg[col];
      #pragma unroll
      for (int r = 0; r < 4; ++r) {
        const int row = m0 + wr * WM + m * 16 + (lane >> 4) * 4 + r;
        const long ci = (long)row * H_ + col;
        out[ci] = x[ci] + ctx[m][n][r] + bv;
      }
    }
  }
}

// ---------------- launch ----------------
extern "C" void kernel_launch(void* const* d_in, const int* in_sizes, int n_in,
                              void* d_out, int out_size, void* d_ws, size_t ws_size,
                              hipStream_t stream)
{
  const float* x      = (const float*)d_in[0];
  const float* fc1_w  = (const float*)d_in[1];
  const float* fc1_b  = (const float*)d_in[2];
  const float* fc2_w  = (const float*)d_in[3];
  const float* fc2_b  = (const float*)d_in[4];
  const float* efc1   = (const float*)d_in[5];
  const float* efc2   = (const float*)d_in[6];
  const float* etask  = (const float*)d_in[7];
  const float* q_w    = (const float*)d_in[8];
  const float* q_b    = (const float*)d_in[9];
  const float* k_w    = (const float*)d_in[10];
  const float* k_b    = (const float*)d_in[11];
  const float* v_w    = (const float*)d_in[12];
  const float* v_b    = (const float*)d_in[13];
  const float* equery = (const float*)d_in[14];
  const float* ekey   = (const float*)d_in[15];
  const float* evalue = (const float*)d_in[16];
  const int*   tptr   = (const int*)d_in[17];
  const int*   sptr   = (const int*)d_in[18];
  float* out = (float*)d_out;

  // workspace carve-up (~249 MiB peak)
  char* w = (char*)d_ws;
  ushort* hidb = (ushort*)w; w += (long)T_ * M_ * H_ * 2;       // 192 MiB
  char* regionA = w;         w += (long)M_ * H_ * 2;            // 32 MiB (xb, later scB)
  ushort* xb  = (ushort*)regionA;
  float*  scB = (float*)regionA;          // alias: xb dead before scB written
  ushort* h1b  = (ushort*)w; w += (long)M_ * A_ * 2;            // 16 MiB
  ushort* w1b  = (ushort*)w; w += (long)A_ * H_ * 2;            // 1 MiB
  ushort* W2g  = (ushort*)w; w += (long)T_ * H_ * A_ * 2;       // 6 MiB
  ushort* vwb  = (ushort*)w; w += (long)H_ * H_ * 2;            // 2 MiB
  ushort* kqw  = (ushort*)w; w += (long)64 * H_ * 2;            // 128 KiB
  float*  kqb  = (float*)w;  w += 64 * 4;
  float*  g1   = (float*)w;  w += T_ * A_ * 4;
  float*  g2   = (float*)w;  w += T_ * H_ * 4;
  float*  vbg  = (float*)w;  w += H_ * 4;
  (void)ws_size; (void)in_sizes; (void)n_in; (void)out_size;

  // 1. gates + effective q/k weights + gated/permuted V weight
  gates_kernel<<<1, 1024, 0, stream>>>(efc1, efc2, tptr, sptr, g1, g2);
  kq_kernel<<<64, 256, 0, stream>>>(etask, q_w, q_b, equery, ekey, k_w, k_b,
                                    tptr, sptr, kqw, kqb);
  conv_vw<<<1024, 256, 0, stream>>>(v_w, v_b, evalue, tptr, sptr, vwb, vbg);

  // 2. conversions / gated weights
  conv_bf16<<<2048, 256, 0, stream>>>(x, xb, (long)M_ * H_);
  conv_bf16<<<256, 256, 0, stream>>>(fc1_w, w1b, (long)A_ * H_);
  conv_w2g<<<3072, 256, 0, stream>>>(fc2_w, g1, W2g);

  // 3. h1 = gelu(x @ fc1_w^T + fc1_b)           [16384 x 512], K=1024
  gemm_bt<128, 128, 0><<<dim3(M_ / 128, A_ / 128, 1), 256, 0, stream>>>(
      xb, w1b, h1b, fc1_b, nullptr, M_, A_, H_, 0, 0, 0, 0, 0.f);

  // 4. hid[ti] = gelu(h1 @ (fc2_w*g1[ti])^T + fc2_b) * g2[ti]   [6][16384 x 1024], K=512
  gemm_bt<128, 128, 1><<<dim3(M_ / 128, H_ / 128, T_), 256, 0, stream>>>(
      h1b, W2g, hidb, fc2_b, g2, M_, H_, A_,
      0, (long)H_ * A_, HID_STRIDE, H_, 0.f);

  // 5. scores[ti] = (hid[ti] @ kq_w^T + kq_b) / 8    [6][16384 x 64], K=1024
  gemm_bt<128, 64, 2><<<dim3(M_ / 128, 1, T_), 256, 0, stream>>>(
      hidb, kqw, scB, kqb, nullptr, M_, 64, H_,
      HID_STRIDE, 0, SC_STRIDE, 0, 0.125f);

  // 6. fused softmax + V-GEMM over 6 tasks + weighted context + residual
  fusedv_kernel<<<dim3(M_ / 128, H_ / 128, 1), 256, 0, stream>>>(
      hidb, vwb, scB, vbg, x, out);
}

// Round 15
// 551.091 us; speedup vs baseline: 1.5476x; 1.5476x over previous
//
#include <hip/hip_runtime.h>
#include <hip/hip_bf16.h>

// Problem constants (setup_inputs: B=8,S=2048,H=1024,A=512,N=10, t=5, s=400)
static constexpr int B_ = 8, S_ = 2048, H_ = 1024, A_ = 512;
static constexpr int M_ = B_ * S_;          // 16384 rows (b,s)
static constexpr int T_ = 6;                // t+1
static constexpr long HID_STRIDE = (long)M_ * H_;   // 16777216 elems
static constexpr long SC_STRIDE  = (long)M_ * 64;   // 1048576 elems

typedef __attribute__((ext_vector_type(4))) float f32x4;
typedef __attribute__((ext_vector_type(8))) short bf16x8;

__device__ __forceinline__ float bf2f(ushort u){ return __uint_as_float(((unsigned)u) << 16); }
__device__ __forceinline__ ushort f2bf(float f){
  __hip_bfloat16 h = __float2bfloat16(f);
  return __builtin_bit_cast(unsigned short, h);
}
__device__ __forceinline__ float geluf(float x){
  return 0.5f * x * (1.0f + erff(x * 0.70710678118654752440f));
}
__device__ __forceinline__ float sigm(float x){ return 1.0f / (1.0f + __expf(-x)); }

__device__ __forceinline__ void gload_lds16(const void* g, void* l){
  __builtin_amdgcn_global_load_lds((const __attribute__((address_space(1))) void*)g,
                                   (__attribute__((address_space(3))) void*)l, 16, 0, 0);
}

// ---------------- prep kernels ----------------

__global__ void gates_kernel(const float* __restrict__ efc1, const float* __restrict__ efc2,
                             const int* __restrict__ tptr, const int* __restrict__ sptr,
                             float* __restrict__ g1, float* __restrict__ g2)
{
  const int h = threadIdx.x;          // 0..1023
  const int t = *tptr;
  const float s = (float)(*sptr);
  #pragma unroll
  for (int ti = 0; ti < T_; ++ti) {
    const int task = (ti == 0) ? t : (ti - 1);
    const float scl = (ti == 0) ? s : 400.0f;
    g2[ti * H_ + h] = sigm(scl * efc2[task * H_ + h]);
    if (h < A_) g1[ti * A_ + h] = sigm(scl * efc1[task * A_ + h]);
  }
}

__global__ void kq_kernel(const float* __restrict__ etask, const float* __restrict__ q_w,
                          const float* __restrict__ q_b, const float* __restrict__ equery,
                          const float* __restrict__ ekey, const float* __restrict__ k_w,
                          const float* __restrict__ k_b,
                          const int* __restrict__ tptr, const int* __restrict__ sptr,
                          ushort* __restrict__ kqw, float* __restrict__ kqb)
{
  __shared__ float qg[16];
  const int d = blockIdx.x;           // 0..63
  const int tid = threadIdx.x;        // 256 threads
  const int t = *tptr;
  const float s = (float)(*sptr);
  if (tid < 16) {
    const int hp = tid * 64 + d;
    const float* et = etask + (long)t * H_;
    const float* qw = q_w + (long)hp * H_;
    float acc = 0.f;
    for (int i = 0; i < H_; ++i) acc += et[i] * qw[i];
    float qv = (acc + q_b[hp]) * sigm(s * equery[t * H_ + hp]);
    qg[tid] = qv * sigm(s * ekey[t * H_ + hp]);
  }
  __syncthreads();
  for (int hh = tid; hh < H_; hh += 256) {
    float acc = 0.f;
    #pragma unroll
    for (int n = 0; n < 16; ++n) acc += qg[n] * k_w[(long)(n * 64 + d) * H_ + hh];
    kqw[d * H_ + hh] = f2bf(acc);
  }
  if (tid == 0) {
    float acc = 0.f;
    #pragma unroll
    for (int n = 0; n < 16; ++n) acc += qg[n] * k_b[n * 64 + d];
    kqb[d] = acc;
  }
}

__global__ void conv_bf16(const float* __restrict__ in, ushort* __restrict__ outp, long n)
{
  long i = ((long)blockIdx.x * blockDim.x + threadIdx.x) * 4;
  const long stride = (long)gridDim.x * blockDim.x * 4;
  for (; i < n; i += stride) {
    float4 v = *(const float4*)(in + i);
    ushort4 o;
    o.x = f2bf(v.x); o.y = f2bf(v.y); o.z = f2bf(v.z); o.w = f2bf(v.w);
    *(ushort4*)(outp + i) = o;
  }
}

__global__ void conv_w2g(const float* __restrict__ fc2w, const float* __restrict__ g1,
                         ushort* __restrict__ W2g)
{
  const long total = (long)T_ * H_ * A_;
  long i = ((long)blockIdx.x * blockDim.x + threadIdx.x) * 4;
  if (i >= total) return;
  const int ti = (int)(i / ((long)H_ * A_));
  const long r = i - (long)ti * H_ * A_;
  const int a = (int)(r & (A_ - 1));
  float4 wv = *(const float4*)(fc2w + r);
  const float* g = g1 + ti * A_ + a;
  ushort4 o;
  o.x = f2bf(wv.x * g[0]); o.y = f2bf(wv.y * g[1]);
  o.z = f2bf(wv.z * g[2]); o.w = f2bf(wv.w * g[3]);
  *(ushort4*)(W2g + i) = o;
}

// Permuted gated V weight: row f (output feature) <- v_w[hp]*gv[hp], hp=(f&15)*64+(f>>4)
__global__ void conv_vw(const float* __restrict__ v_w, const float* __restrict__ v_b,
                        const float* __restrict__ evalue,
                        const int* __restrict__ tptr, const int* __restrict__ sptr,
                        ushort* __restrict__ vwb, float* __restrict__ vbg)
{
  const int t = *tptr;
  const float s = (float)(*sptr);
  long i = ((long)blockIdx.x * blockDim.x + threadIdx.x) * 4;
  if (i < (long)H_ * H_) {
    const int f = (int)(i >> 10);
    const int hp = ((f & 15) << 6) + (f >> 4);
    const float g = sigm(s * evalue[t * H_ + hp]);
    float4 wv = *(const float4*)(v_w + ((long)hp << 10) + (i & 1023));
    ushort4 o;
    o.x = f2bf(wv.x * g); o.y = f2bf(wv.y * g);
    o.z = f2bf(wv.z * g); o.w = f2bf(wv.w * g);
    *(ushort4*)(vwb + i) = o;
  }
  const long j = (long)blockIdx.x * blockDim.x + threadIdx.x;
  if (j < H_) {
    const int hp = (((int)j & 15) << 6) + ((int)j >> 4);
    vbg[j] = v_b[hp] * sigm(s * evalue[t * H_ + hp]);
  }
}

// ---------------- GEMM: C = epi(A @ B^T + bias) ----------------
// Best measured (round 8): 3-buffer single-barrier depth-2 pipeline; per step:
// vmcnt(N) -> barrier -> ds_read issue -> stage(t+2) -> lgkmcnt(0) -> MFMA.
// T2 XOR-swizzle (conflicts=0), T4 counted vmcnt, T5 setprio.
// EPI: 0 = gelu->bf16, 1 = gelu*scale[col]->bf16, 2 = (acc+bias)*postmul->f32
template<int BM, int BN, int EPI>
__global__ __launch_bounds__(256)
void gemm_bt(const ushort* __restrict__ A, const ushort* __restrict__ Bm,
             void* __restrict__ C, const float* __restrict__ bias,
             const float* __restrict__ scale,
             int M, int N, int K,
             long strideAz, long strideBz, long strideCz, int strideSz,
             float postmul)
{
  constexpr int BK = 32;
  constexpr int WM = BM / 2, WN = BN / 2;
  constexpr int MI = WM / 16, NI = WN / 16;
  constexpr int L = BM / 64 + BN / 64;     // loads per thread per stage
  __shared__ alignas(16) ushort As[3][BM * BK];
  __shared__ alignas(16) ushort Bs[3][BN * BK];

  const int z = blockIdx.z;
  A  += (long)z * strideAz;
  Bm += (long)z * strideBz;

  const int gx = gridDim.x, gy = gridDim.y;
  int flat = blockIdx.y * gx + blockIdx.x;
  const int nwg = gx * gy;
  if ((nwg & 7) == 0) flat = (flat & 7) * (nwg >> 3) + (flat >> 3);
  const int m0 = (flat / gy) * BM, n0 = (flat % gy) * BN;

  const int tid = threadIdx.x, lane = tid & 63, wid = tid >> 6;
  const int wr = wid >> 1, wc = wid & 1;
  const int srow = tid >> 2;
  const int scol = (tid & 3) * 8;
  const int scol_src = (((tid & 3) ^ ((tid >> 3) & 3))) * 8;

  auto stage = [&](int buf, int kk) {
    #pragma unroll
    for (int i = 0; i < BM / 64; ++i)
      gload_lds16(A + (long)(m0 + i * 64 + srow) * K + kk + scol_src,
                  &As[buf][(i * 64 + srow) * BK + scol]);
    #pragma unroll
    for (int i = 0; i < BN / 64; ++i)
      gload_lds16(Bm + (long)(n0 + i * 64 + srow) * K + kk + scol_src,
                  &Bs[buf][(i * 64 + srow) * BK + scol]);
  };

  f32x4 acc[MI][NI] = {};
  const int NT = K / BK;
  const int ks = (((lane >> 4) ^ ((lane >> 1) & 3))) * 8;

  stage(0, 0);
  stage(1, BK);

  int cur = 0;
  for (int t = 0; t < NT; ++t) {
    if (t + 1 < NT) {
      if constexpr (L == 4) asm volatile("s_waitcnt vmcnt(4)" ::: "memory");
      else                  asm volatile("s_waitcnt vmcnt(3)" ::: "memory");
    } else {
      asm volatile("s_waitcnt vmcnt(0)" ::: "memory");
    }
    __builtin_amdgcn_s_barrier();            // tile t staged; buf (cur-1) fully read
    __builtin_amdgcn_sched_barrier(0);

    bf16x8 af[MI], bfr[NI];
    #pragma unroll
    for (int m = 0; m < MI; ++m)
      af[m] = *(const bf16x8*)&As[cur][(wr * WM + m * 16 + (lane & 15)) * BK + ks];
    #pragma unroll
    for (int n = 0; n < NI; ++n)
      bfr[n] = *(const bf16x8*)&Bs[cur][(wc * WN + n * 16 + (lane & 15)) * BK + ks];
    __builtin_amdgcn_sched_barrier(0);       // pin: ds_reads issue before stage

    if (t + 2 < NT) {
      int nb = cur + 2; if (nb >= 3) nb -= 3;
      stage(nb, (t + 2) * BK);               // overlaps ds_read latency
    }

    asm volatile("s_waitcnt lgkmcnt(0)" ::: "memory");
    __builtin_amdgcn_sched_barrier(0);

    __builtin_amdgcn_s_setprio(1);
    #pragma unroll
    for (int m = 0; m < MI; ++m)
      #pragma unroll
      for (int n = 0; n < NI; ++n)
        acc[m][n] = __builtin_amdgcn_mfma_f32_16x16x32_bf16(af[m], bfr[n], acc[m][n], 0, 0, 0);
    __builtin_amdgcn_s_setprio(0);
    ++cur; if (cur >= 3) cur = 0;
  }

  const float* sc = (EPI == 1) ? (scale + (long)z * strideSz) : nullptr;
  #pragma unroll
  for (int m = 0; m < MI; ++m) {
    #pragma unroll
    for (int n = 0; n < NI; ++n) {
      const int col = n0 + wc * WN + n * 16 + (lane & 15);
      const float bv = bias[col];
      #pragma unroll
      for (int r = 0; r < 4; ++r) {
        const int row = m0 + wr * WM + m * 16 + (lane >> 4) * 4 + r;
        const float v = acc[m][n][r] + bv;
        const long ci = (long)z * strideCz + (long)row * N + col;
        if constexpr (EPI == 0) {
          ((ushort*)C)[ci] = f2bf(geluf(v));
        } else if constexpr (EPI == 1) {
          ((ushort*)C)[ci] = f2bf(geluf(v) * sc[col]);
        } else {
          ((float*)C)[ci] = v * postmul;
        }
      }
    }
  }
}

// ---------------- fused softmax + V-GEMM + context + residual ----------------
// out[row][f] = x[row][f] + vbg[f] + sum_ti p[ti][row][f>>4] * (hid[ti][row] . vwb[f])
// (bias folds out: sum_ti p = 1). Softmax computed in prologue into p_lds.
// BM=128, BN=128, wave tile 64x64; 3-buffer single-barrier pipeline (round-8 best).
__global__ __launch_bounds__(256)
void fusedv_kernel(const ushort* __restrict__ hidb, const ushort* __restrict__ vwb,
                   const float* __restrict__ scB, const float* __restrict__ vbg,
                   const float* __restrict__ x, float* __restrict__ out)
{
  constexpr int BM = 128, BN = 128, BK = 32;
  constexpr int WM = 64, WN = 64, MI = 4, NI = 4;
  constexpr int NT = T_ * 32;
  __shared__ alignas(16) ushort As[3][BM * BK];
  __shared__ alignas(16) ushort Bs[3][BN * BK];
  __shared__ alignas(16) float p_lds[T_ * BM * 8];   // 24 KB

  const int gx = gridDim.x, gy = gridDim.y;   // (128, 8)
  int flat = blockIdx.y * gx + blockIdx.x;
  const int nwg = gx * gy;
  flat = (flat & 7) * (nwg >> 3) + (flat >> 3);
  const int m0 = (flat / gy) * BM, n0 = (flat % gy) * BN;
  const int d0 = n0 >> 4;

  const int tid = threadIdx.x, lane = tid & 63, wid = tid >> 6;
  const int wr = wid >> 1, wc = wid & 1;
  const int srow = tid >> 2;
  const int scol = (tid & 3) * 8;
  const int scol_src = (((tid & 3) ^ ((tid >> 3) & 3))) * 8;
  const int ks = (((lane >> 4) ^ ((lane >> 1) & 3))) * 8;

  auto stageAB = [&](int buf, int kt) {
    const int ti = kt >> 5;
    const int kk = (kt & 31) << 5;
    const ushort* Ap = hidb + (long)ti * HID_STRIDE;
    #pragma unroll
    for (int i = 0; i < 2; ++i)
      gload_lds16(Ap + (long)(m0 + i * 64 + srow) * H_ + kk + scol_src,
                  &As[buf][(i * 64 + srow) * BK + scol]);
    #pragma unroll
    for (int i = 0; i < 2; ++i)
      gload_lds16(vwb + (long)(n0 + i * 64 + srow) * H_ + kk + scol_src,
                  &Bs[buf][(i * 64 + srow) * BK + scol]);
  };

  // prologue: stage tile 0 (async) + softmax into p_lds (overlaps)
  stageAB(0, 0);
  #pragma unroll
  for (int c = 0; c < 4; ++c) {
    const int cell = tid + c * 256;          // 0..1023 = 128 rows x 8 d
    const int row = cell >> 3, dl = cell & 7;
    const long base = (long)(m0 + row) * 64 + d0 + dl;
    float v[T_]; float mx = -1e30f;
    #pragma unroll
    for (int ti = 0; ti < T_; ++ti) {
      v[ti] = scB[(long)ti * SC_STRIDE + base];
      mx = fmaxf(mx, v[ti]);
    }
    float sum = 0.f;
    #pragma unroll
    for (int ti = 0; ti < T_; ++ti) { v[ti] = __expf(v[ti] - mx); sum += v[ti]; }
    const float inv = 1.0f / sum;
    #pragma unroll
    for (int ti = 0; ti < T_; ++ti) p_lds[(ti * BM + row) * 8 + dl] = v[ti] * inv;
  }
  asm volatile("s_waitcnt lgkmcnt(0)" ::: "memory");  // p_lds writes retired
  stageAB(1, 1);

  const f32x4 zero = {};
  f32x4 ctx[MI][NI] = {};
  f32x4 acc[MI][NI] = {};

  int cur = 0;
  for (int kt = 0; kt < NT; ++kt) {
    if (kt + 1 < NT) asm volatile("s_waitcnt vmcnt(4)" ::: "memory");
    else             asm volatile("s_waitcnt vmcnt(0)" ::: "memory");
    __builtin_amdgcn_s_barrier();            // tile kt staged (and p_lds on kt==0)
    __builtin_amdgcn_sched_barrier(0);

    bf16x8 af[MI], bfr[NI];
    #pragma unroll
    for (int m = 0; m < MI; ++m)
      af[m] = *(const bf16x8*)&As[cur][(wr * WM + m * 16 + (lane & 15)) * BK + ks];
    #pragma unroll
    for (int n = 0; n < NI; ++n)
      bfr[n] = *(const bf16x8*)&Bs[cur][(wc * WN + n * 16 + (lane & 15)) * BK + ks];
    __builtin_amdgcn_sched_barrier(0);       // pin: ds_reads issue before stage

    if (kt + 2 < NT) {
      int nb = cur + 2; if (nb >= 3) nb -= 3;
      stageAB(nb, kt + 2);                   // overlaps ds_read latency
    }

    asm volatile("s_waitcnt lgkmcnt(0)" ::: "memory");
    __builtin_amdgcn_sched_barrier(0);

    __builtin_amdgcn_s_setprio(1);
    #pragma unroll
    for (int m = 0; m < MI; ++m)
      #pragma unroll
      for (int n = 0; n < NI; ++n)
        acc[m][n] = __builtin_amdgcn_mfma_f32_16x16x32_bf16(af[m], bfr[n], acc[m][n], 0, 0, 0);
    __builtin_amdgcn_s_setprio(0);

    if ((kt & 31) == 31) {                   // task boundary: fold p * acc into ctx
      const int ti = kt >> 5;
      #pragma unroll
      for (int m = 0; m < MI; ++m) {
        #pragma unroll
        for (int r = 0; r < 4; ++r) {
          const int rowl = wr * WM + m * 16 + (lane >> 4) * 4 + r;
          const f32x4 pv = *(const f32x4*)&p_lds[(ti * BM + rowl) * 8 + wc * 4];
          #pragma unroll
          for (int n = 0; n < NI; ++n)
            ctx[m][n][r] += pv[n] * acc[m][n][r];
        }
        #pragma unroll
        for (int n = 0; n < NI; ++n) acc[m][n] = zero;
      }
    }
    ++cur; if (cur >= 3) cur = 0;
  }

  #pragma unroll
  for (int m = 0; m < MI; ++m) {
    #pragma unroll
    for (int n = 0; n < NI; ++n) {
      const int col = n0 + wc * WN + n * 16 + (lane & 15);
      const float bv = vbg[col];
      #pragma unroll
      for (int r = 0; r < 4; ++r) {
        const int row = m0 + wr * WM + m * 16 + (lane >> 4) * 4 + r;
        const long ci = (long)row * H_ + col;
        out[ci] = x[ci] + ctx[m][n][r] + bv;
      }
    }
  }
}

// ---------------- launch ----------------
extern "C" void kernel_launch(void* const* d_in, const int* in_sizes, int n_in,
                              void* d_out, int out_size, void* d_ws, size_t ws_size,
                              hipStream_t stream)
{
  const float* x      = (const float*)d_in[0];
  const float* fc1_w  = (const float*)d_in[1];
  const float* fc1_b  = (const float*)d_in[2];
  const float* fc2_w  = (const float*)d_in[3];
  const float* fc2_b  = (const float*)d_in[4];
  const float* efc1   = (const float*)d_in[5];
  const float* efc2   = (const float*)d_in[6];
  const float* etask  = (const float*)d_in[7];
  const float* q_w    = (const float*)d_in[8];
  const float* q_b    = (const float*)d_in[9];
  const float* k_w    = (const float*)d_in[10];
  const float* k_b    = (const float*)d_in[11];
  const float* v_w    = (const float*)d_in[12];
  const float* v_b    = (const float*)d_in[13];
  const float* equery = (const float*)d_in[14];
  const float* ekey   = (const float*)d_in[15];
  const float* evalue = (const float*)d_in[16];
  const int*   tptr   = (const int*)d_in[17];
  const int*   sptr   = (const int*)d_in[18];
  float* out = (float*)d_out;

  // workspace carve-up (~249 MiB peak)
  char* w = (char*)d_ws;
  ushort* hidb = (ushort*)w; w += (long)T_ * M_ * H_ * 2;       // 192 MiB
  char* regionA = w;         w += (long)M_ * H_ * 2;            // 32 MiB (xb, later scB)
  ushort* xb  = (ushort*)regionA;
  float*  scB = (float*)regionA;          // alias: xb dead before scB written
  ushort* h1b  = (ushort*)w; w += (long)M_ * A_ * 2;            // 16 MiB
  ushort* w1b  = (ushort*)w; w += (long)A_ * H_ * 2;            // 1 MiB
  ushort* W2g  = (ushort*)w; w += (long)T_ * H_ * A_ * 2;       // 6 MiB
  ushort* vwb  = (ushort*)w; w += (long)H_ * H_ * 2;            // 2 MiB
  ushort* kqw  = (ushort*)w; w += (long)64 * H_ * 2;            // 128 KiB
  float*  kqb  = (float*)w;  w += 64 * 4;
  float*  g1   = (float*)w;  w += T_ * A_ * 4;
  float*  g2   = (float*)w;  w += T_ * H_ * 4;
  float*  vbg  = (float*)w;  w += H_ * 4;
  (void)ws_size; (void)in_sizes; (void)n_in; (void)out_size;

  // 1. gates + effective q/k weights + gated/permuted V weight
  gates_kernel<<<1, 1024, 0, stream>>>(efc1, efc2, tptr, sptr, g1, g2);
  kq_kernel<<<64, 256, 0, stream>>>(etask, q_w, q_b, equery, ekey, k_w, k_b,
                                    tptr, sptr, kqw, kqb);
  conv_vw<<<1024, 256, 0, stream>>>(v_w, v_b, evalue, tptr, sptr, vwb, vbg);

  // 2. conversions / gated weights
  conv_bf16<<<2048, 256, 0, stream>>>(x, xb, (long)M_ * H_);
  conv_bf16<<<256, 256, 0, stream>>>(fc1_w, w1b, (long)A_ * H_);
  conv_w2g<<<3072, 256, 0, stream>>>(fc2_w, g1, W2g);

  // 3. h1 = gelu(x @ fc1_w^T + fc1_b)           [16384 x 512], K=1024
  gemm_bt<128, 128, 0><<<dim3(M_ / 128, A_ / 128, 1), 256, 0, stream>>>(
      xb, w1b, h1b, fc1_b, nullptr, M_, A_, H_, 0, 0, 0, 0, 0.f);

  // 4. hid[ti] = gelu(h1 @ (fc2_w*g1[ti])^T + fc2_b) * g2[ti]   [6][16384 x 1024], K=512
  gemm_bt<128, 128, 1><<<dim3(M_ / 128, H_ / 128, T_), 256, 0, stream>>>(
      h1b, W2g, hidb, fc2_b, g2, M_, H_, A_,
      0, (long)H_ * A_, HID_STRIDE, H_, 0.f);

  // 5. scores[ti] = (hid[ti] @ kq_w^T + kq_b) / 8    [6][16384 x 64], K=1024
  gemm_bt<128, 64, 2><<<dim3(M_ / 128, 1, T_), 256, 0, stream>>>(
      hidb, kqw, scB, kqb, nullptr, M_, 64, H_,
      HID_STRIDE, 0, SC_STRIDE, 0, 0.125f);

  // 6. fused softmax + V-GEMM over 6 tasks + weighted context + residual
  fusedv_kernel<<<dim3(M_ / 128, H_ / 128, 1), 256, 0, stream>>>(
      hidb, vwb, scB, vbg, x, out);
}